// Round 1
// baseline (333.587 us; speedup 1.0000x reference)
//
#include <hip/hip_runtime.h>
#include <hip/hip_bf16.h>

#define BZ 8192
#define PP 1024
#define DD 1024
#define KSEL 8

// ws layout (in floats):
//   [0, 1024)        inv-norm of keys rows
//   [1024, 9216)     inv-norm of ppg rows
//   [9216, 17408)    per-row sum of top-8 scores
//   [17408, 25600)   per-row entropy
//   [25600, 91136)   top-8 indices per row (as int)
#define WS_INVK 0
#define WS_INVP 1024
#define WS_SCORE 9216
#define WS_ENT 17408
#define WS_IDX 25600

// ---------------- Kernel 1: row inverse norms (keys then ppg) ----------------
__global__ __launch_bounds__(256) void norms_kernel(const float* __restrict__ ppg,
                                                    const float* __restrict__ keys,
                                                    float* __restrict__ ws) {
  int blk = blockIdx.x;
  const float* src;
  float* dst;
  if (blk < PP) { src = keys + (size_t)blk * DD; dst = ws + WS_INVK + blk; }
  else          { src = ppg + (size_t)(blk - PP) * DD; dst = ws + WS_INVP + (blk - PP); }
  int t = threadIdx.x;
  float4 v = ((const float4*)src)[t];           // 256 * 4 = 1024 floats
  float s = v.x*v.x + v.y*v.y + v.z*v.z + v.w*v.w;
  __shared__ float red[4];
  #pragma unroll
  for (int o = 32; o > 0; o >>= 1) s += __shfl_down(s, o);
  if ((t & 63) == 0) red[t >> 6] = s;
  __syncthreads();
  if (t == 0) {
    float tot = red[0] + red[1] + red[2] + red[3];
    *dst = 1.0f / fmaxf(sqrtf(tot), 1e-8f);
  }
}

// ---------------- Kernel 2: fp32 GEMM  cos[b][p] = dot(ppg_b, keys_p)*ia*ik --
#define BM 128
#define BN 128
#define BK 16

__global__ __launch_bounds__(256) void gemm_kernel(const float* __restrict__ A,
                                                   const float* __restrict__ B,
                                                   const float* __restrict__ ws,
                                                   float* __restrict__ C) {
  __shared__ float As[BK][BM];
  __shared__ float Bs[BK][BN];
  int t = threadIdx.x;
  int bm0 = (blockIdx.x / (PP / BN)) * BM;
  int bn0 = (blockIdx.x % (PP / BN)) * BN;
  int tx = t & 15, ty = t >> 4;
  float acc[8][8] = {};

  int r = t & 127;
  const float* src = (t < 128) ? (A + (size_t)(bm0 + r) * DD)
                               : (B + (size_t)(bn0 + r) * DD);
  float* dstbase = (t < 128) ? &As[0][0] : &Bs[0][0];

  for (int k0 = 0; k0 < DD; k0 += BK) {
    // stage: one row of 16 floats per thread, stored transposed [kk][row]
    #pragma unroll
    for (int q = 0; q < 4; ++q) {
      float4 v = *(const float4*)(src + k0 + q * 4);
      dstbase[(q * 4 + 0) * 128 + r] = v.x;
      dstbase[(q * 4 + 1) * 128 + r] = v.y;
      dstbase[(q * 4 + 2) * 128 + r] = v.z;
      dstbase[(q * 4 + 3) * 128 + r] = v.w;
    }
    __syncthreads();
    #pragma unroll
    for (int kk = 0; kk < BK; ++kk) {
      float a[8], b[8];
      *(float4*)&a[0] = *(const float4*)&As[kk][ty * 8];
      *(float4*)&a[4] = *(const float4*)&As[kk][ty * 8 + 4];
      *(float4*)&b[0] = *(const float4*)&Bs[kk][tx * 8];
      *(float4*)&b[4] = *(const float4*)&Bs[kk][tx * 8 + 4];
      #pragma unroll
      for (int i = 0; i < 8; ++i)
        #pragma unroll
        for (int j = 0; j < 8; ++j)
          acc[i][j] = fmaf(a[i], b[j], acc[i][j]);
    }
    __syncthreads();
  }

  const float* invK = ws + WS_INVK;
  const float* invP = ws + WS_INVP;
  #pragma unroll
  for (int i = 0; i < 8; ++i) {
    int row = bm0 + ty * 8 + i;
    float ia = invP[row];
    #pragma unroll
    for (int j = 0; j < 8; j += 4) {
      int col = bn0 + tx * 8 + j;
      float4 o;
      o.x = acc[i][j + 0] * ia * invK[col + 0];
      o.y = acc[i][j + 1] * ia * invK[col + 1];
      o.z = acc[i][j + 2] * ia * invK[col + 2];
      o.w = acc[i][j + 3] * ia * invK[col + 3];
      *(float4*)(C + (size_t)row * PP + col) = o;
    }
  }
}

// ---------------- Kernel 3: per-row top-8 + entropy -------------------------
__global__ __launch_bounds__(256) void topk_kernel(const float* __restrict__ cosm,
                                                   float* __restrict__ ws) {
  int row = blockIdx.x;
  int t = threadIdx.x;
  const float* crow = cosm + (size_t)row * PP;
  float4 cv = ((const float4*)crow)[t];
  float c[4] = {cv.x, cv.y, cv.z, cv.w};

  __shared__ float redf[4];
  __shared__ float redz[4], redw[4];

  // ---- entropy of softmax(score_) with score_ = 1 - cos ----
  float mn = fminf(fminf(c[0], c[1]), fminf(c[2], c[3]));
  float rr = mn;
  #pragma unroll
  for (int o = 32; o > 0; o >>= 1) rr = fminf(rr, __shfl_down(rr, o));
  if ((t & 63) == 0) redf[t >> 6] = rr;
  __syncthreads();
  float m = 1.0f - fminf(fminf(redf[0], redf[1]), fminf(redf[2], redf[3]));  // max score_

  float z = 0.f, w = 0.f;
  #pragma unroll
  for (int j = 0; j < 4; ++j) {
    float s = 1.0f - c[j];
    float e = expf(s - m);
    z += e;
    w += s * e;
  }
  #pragma unroll
  for (int o = 32; o > 0; o >>= 1) { z += __shfl_down(z, o); w += __shfl_down(w, o); }
  if ((t & 63) == 0) { redz[t >> 6] = z; redw[t >> 6] = w; }
  __syncthreads();
  if (t == 0) {
    float zT = redz[0] + redz[1] + redz[2] + redz[3];
    float wT = redw[0] + redw[1] + redw[2] + redw[3];
    ws[WS_ENT + row] = m + logf(zT) - wT / zT;
  }

  // ---- top-8 largest cos (set only; order irrelevant downstream) ----
  __shared__ float wv[4];
  __shared__ int wi[4];
  __shared__ float bval;
  __shared__ int bidx;
  __shared__ int sel[KSEL];
  unsigned used = 0;
  float score_sum = 0.f;

  for (int it = 0; it < KSEL; ++it) {
    float v = -1e30f; int vi = -1;
    #pragma unroll
    for (int j = 0; j < 4; ++j) {
      if (!((used >> j) & 1)) {
        float cj = c[j];
        int gi = t * 4 + j;
        if (cj > v || (cj == v && gi < vi)) { v = cj; vi = gi; }
      }
    }
    #pragma unroll
    for (int o = 32; o > 0; o >>= 1) {
      float ov = __shfl_down(v, o);
      int oi = __shfl_down(vi, o);
      if (ov > v || (ov == v && oi >= 0 && (vi < 0 || oi < vi))) { v = ov; vi = oi; }
    }
    if ((t & 63) == 0) { wv[t >> 6] = v; wi[t >> 6] = vi; }
    __syncthreads();
    if (t == 0) {
      float bv = wv[0]; int bi = wi[0];
      #pragma unroll
      for (int q = 1; q < 4; ++q)
        if (wv[q] > bv || (wv[q] == bv && wi[q] < bi)) { bv = wv[q]; bi = wi[q]; }
      bval = bv; bidx = bi; sel[it] = bi;
    }
    __syncthreads();
    int bi = bidx;
    score_sum += 1.0f - bval;
    if ((bi >> 2) == t) used |= 1u << (bi & 3);
    __syncthreads();
  }

  if (t == 0) ws[WS_SCORE + row] = score_sum;
  if (t < KSEL) ((int*)(ws + WS_IDX))[row * KSEL + t] = sel[t];
}

// ---------------- Kernel 4: gather + conv + mean + normalize + add ----------
__global__ __launch_bounds__(256) void prompt_kernel(const float* __restrict__ ppg,
                                                     const float* __restrict__ pool,
                                                     const float* __restrict__ cw,
                                                     const float* __restrict__ cb,
                                                     const float* __restrict__ ws,
                                                     float* __restrict__ out) {
  int row = blockIdx.x;
  int t = threadIdx.x;
  const int* idx = (const int*)(ws + WS_IDX) + row * KSEL;
  float w0 = cw[0], w1 = cw[1], w2 = cw[2], bb = cb[0];
  int d0 = t * 4;

  float a0 = 0.f, a1 = 0.f, a2 = 0.f, a3 = 0.f;
  #pragma unroll
  for (int j = 0; j < KSEL; ++j) {
    int r = idx[j];
    const float* src = pool + (size_t)r * DD;
    float4 x = *(const float4*)(src + d0);
    float xm = (d0 > 0) ? src[d0 - 1] : 0.f;
    float xp = (d0 + 4 < DD) ? src[d0 + 4] : 0.f;
    float y0 = fmaf(w0, xm,  fmaf(w1, x.x, fmaf(w2, x.y, bb)));
    float y1 = fmaf(w0, x.x, fmaf(w1, x.y, fmaf(w2, x.z, bb)));
    float y2 = fmaf(w0, x.y, fmaf(w1, x.z, fmaf(w2, x.w, bb)));
    float y3 = fmaf(w0, x.z, fmaf(w1, x.w, fmaf(w2, xp, bb)));
    a0 += fmaxf(y0, 0.f);
    a1 += fmaxf(y1, 0.f);
    a2 += fmaxf(y2, 0.f);
    a3 += fmaxf(y3, 0.f);
  }
  float p0 = a0 * 0.125f, p1 = a1 * 0.125f, p2 = a2 * 0.125f, p3 = a3 * 0.125f;

  // block min/max over the 1024 prompt values
  __shared__ float rmin[4], rmax[4];
  float lmin = fminf(fminf(p0, p1), fminf(p2, p3));
  float lmax = fmaxf(fmaxf(p0, p1), fmaxf(p2, p3));
  #pragma unroll
  for (int o = 32; o > 0; o >>= 1) {
    lmin = fminf(lmin, __shfl_down(lmin, o));
    lmax = fmaxf(lmax, __shfl_down(lmax, o));
  }
  if ((t & 63) == 0) { rmin[t >> 6] = lmin; rmax[t >> 6] = lmax; }
  __syncthreads();
  float pmin = fminf(fminf(rmin[0], rmin[1]), fminf(rmin[2], rmin[3]));
  float pmax = fmaxf(fmaxf(rmax[0], rmax[1]), fmaxf(rmax[2], rmax[3]));
  float scale = 2.0f / (pmax - pmin);

  float4 pv = *(const float4*)(ppg + (size_t)row * DD + d0);
  float4 o;
  o.x = pv.x + (scale * (p0 - pmin) - 1.0f);
  o.y = pv.y + (scale * (p1 - pmin) - 1.0f);
  o.z = pv.z + (scale * (p2 - pmin) - 1.0f);
  o.w = pv.w + (scale * (p3 - pmin) - 1.0f);
  *(float4*)(out + (size_t)row * DD + d0) = o;
}

// ---------------- Kernel 5: deterministic final reduction -------------------
__global__ __launch_bounds__(256) void finalize_kernel(const float* __restrict__ ws,
                                                       float* __restrict__ out) {
  int t = threadIdx.x;
  const float* ss = ws + WS_SCORE;
  const float* ee = ws + WS_ENT;
  float s = 0.f, e = 0.f;
  for (int i = t; i < BZ; i += 256) { s += ss[i]; e += ee[i]; }
  __shared__ float rs[4], re[4];
  #pragma unroll
  for (int o = 32; o > 0; o >>= 1) { s += __shfl_down(s, o); e += __shfl_down(e, o); }
  if ((t & 63) == 0) { rs[t >> 6] = s; re[t >> 6] = e; }
  __syncthreads();
  if (t == 0) {
    float sT = rs[0] + rs[1] + rs[2] + rs[3];
    float eT = re[0] + re[1] + re[2] + re[3];
    out[(size_t)BZ * DD + 0] = sT / (float)(BZ * KSEL);
    out[(size_t)BZ * DD + 1] = eT / (float)BZ;
  }
}

extern "C" void kernel_launch(void* const* d_in, const int* in_sizes, int n_in,
                              void* d_out, int out_size, void* d_ws, size_t ws_size,
                              hipStream_t stream) {
  const float* ppg  = (const float*)d_in[0];
  const float* keys = (const float*)d_in[1];
  const float* pool = (const float*)d_in[2];
  const float* cw   = (const float*)d_in[3];
  const float* cb   = (const float*)d_in[4];
  float* out = (float*)d_out;
  float* ws  = (float*)d_ws;

  hipLaunchKernelGGL(norms_kernel, dim3(PP + BZ), dim3(256), 0, stream, ppg, keys, ws);
  hipLaunchKernelGGL(gemm_kernel, dim3((BZ / BM) * (PP / BN)), dim3(256), 0, stream,
                     ppg, keys, ws, out);
  hipLaunchKernelGGL(topk_kernel, dim3(BZ), dim3(256), 0, stream, out, ws);
  hipLaunchKernelGGL(prompt_kernel, dim3(BZ), dim3(256), 0, stream, ppg, pool, cw, cb, ws, out);
  hipLaunchKernelGGL(finalize_kernel, dim3(1), dim3(256), 0, stream, ws, out);
}

// Round 2
// 174.506 us; speedup vs baseline: 1.9116x; 1.9116x over previous
//
#include <hip/hip_runtime.h>
#include <hip/hip_bf16.h>

#define BZ 8192
#define PP 1024
#define DD 1024
#define KSEL 8

typedef unsigned short u16;
typedef __attribute__((ext_vector_type(8))) short bf16x8;
typedef __attribute__((ext_vector_type(4))) float f32x4;

// ws layout (floats):
//   [0,1024)       inv-norm keys
//   [1024,9216)    inv-norm ppg
//   [9216,17408)   per-row top-8 score sum
//   [17408,25600)  per-row entropy
//   [25600,91136)  top-8 indices (ints)
//   byte 368640 .. : bf16 A_hi, A_lo (16MB each), B_hi, B_lo (2MB each)
#define WS_INVK 0
#define WS_INVP 1024
#define WS_SCORE 9216
#define WS_ENT 17408
#define WS_IDX 25600
#define WS_BF16_BYTE 368640ull
#define WS_NEED (WS_BF16_BYTE + 2ull*16777216ull + 2ull*4194304ull)

__device__ __forceinline__ u16 f2bf(float x) {
  __hip_bfloat16 h = __float2bfloat16(x);
  return *(u16*)&h;
}
__device__ __forceinline__ float bf2f(u16 u) {
  __hip_bfloat16 h; *(u16*)&h = u;
  return __bfloat162float(h);
}
__device__ __forceinline__ void gll16(const void* g, void* l) {
  __builtin_amdgcn_global_load_lds((__attribute__((address_space(1))) void*)g,
                                   (__attribute__((address_space(3))) void*)l, 16, 0, 0);
}

// ---------- Kernel 1: fused fp32->bf16 hi/lo conversion + inverse norms ------
__global__ __launch_bounds__(256) void convert_kernel(const float* __restrict__ ppg,
                                                      const float* __restrict__ keys,
                                                      float* __restrict__ ws) {
  u16* Ahi = (u16*)((char*)ws + WS_BF16_BYTE);
  u16* Alo = Ahi + 8388608;
  u16* Bhi = Alo + 8388608;
  u16* Blo = Bhi + 1048576;

  int blk = blockIdx.x;
  const float* src; u16 *hi, *lo; float* invdst;
  if (blk < PP) {
    src = keys + (size_t)blk * DD;
    hi = Bhi + (size_t)blk * DD; lo = Blo + (size_t)blk * DD;
    invdst = ws + WS_INVK + blk;
  } else {
    int r = blk - PP;
    src = ppg + (size_t)r * DD;
    hi = Ahi + (size_t)r * DD; lo = Alo + (size_t)r * DD;
    invdst = ws + WS_INVP + r;
  }
  int t = threadIdx.x;
  float4 v = ((const float4*)src)[t];
  float x[4] = {v.x, v.y, v.z, v.w};
  u16 h4[4], l4[4];
  float s = 0.f;
  #pragma unroll
  for (int j = 0; j < 4; ++j) {
    h4[j] = f2bf(x[j]);
    l4[j] = f2bf(x[j] - bf2f(h4[j]));
    s += x[j] * x[j];
  }
  *(ushort4*)(hi + t * 4) = *(ushort4*)h4;
  *(ushort4*)(lo + t * 4) = *(ushort4*)l4;

  __shared__ float red[4];
  #pragma unroll
  for (int o = 32; o > 0; o >>= 1) s += __shfl_down(s, o);
  if ((t & 63) == 0) red[t >> 6] = s;
  __syncthreads();
  if (t == 0) {
    float tot = red[0] + red[1] + red[2] + red[3];
    *invdst = 1.0f / fmaxf(sqrtf(tot), 1e-8f);
  }
}

// ---------- Kernel 2: 3-pass bf16 hi/lo MFMA GEMM (m97 structure) -----------
// C[m][n] = dot(A_m, B_n) * invP[m] * invK[n],  M=8192 N=1024 K=1024
#define LDS_AH 0
#define LDS_AL 8192
#define LDS_BH 16384
#define LDS_BL 24576

__global__ __launch_bounds__(256, 2) void gemm_mfma(const float* __restrict__ ws_ro,
                                                    float* __restrict__ C) {
  const u16* Ahi = (const u16*)((const char*)ws_ro + WS_BF16_BYTE);
  const u16* Alo = Ahi + 8388608;
  const u16* Bhi = Alo + 8388608;
  const u16* Blo = Bhi + 1048576;

  __shared__ u16 lds[32768];  // 64 KB: Ahi|Alo|Bhi|Blo tiles, each 128x64 bf16

  int t = threadIdx.x;
  int wid = t >> 6, lane = t & 63;
  int lr = lane & 15, lg = lane >> 4;

  // bijective XCD-chunked swizzle (512 blocks, 8 XCDs -> 64 each)
  int orig = blockIdx.x;
  int wg = (orig & 7) * 64 + (orig >> 3);
  int bm0 = (wg >> 3) * 128;
  int bn0 = (wg & 7) * 128;

  int wm = wid >> 1, wn = wid & 1;  // 2x2 waves, each owns 64x64

  // staging offsets: 4 rounds, slot = r*256+t -> row=s>>3, 16B-group g=s&7
  size_t offA[4], offB[4];
  int ldso[4];
  #pragma unroll
  for (int r = 0; r < 4; ++r) {
    int s = r * 256 + t;
    int row = s >> 3, g = s & 7;
    offA[r] = (size_t)(bm0 + row) * DD + g * 8;
    offB[r] = (size_t)(bn0 + row) * DD + g * 8;
    ldso[r] = (r * 256 + wid * 64) * 8;  // ushort index of wave-uniform base
  }

  f32x4 acc[4][4] = {};

  for (int kt = 0; kt < 16; ++kt) {
    int k0 = kt * 64;
    #pragma unroll
    for (int r = 0; r < 4; ++r) {
      gll16(Ahi + offA[r] + k0, &lds[LDS_AH + ldso[r]]);
      gll16(Alo + offA[r] + k0, &lds[LDS_AL + ldso[r]]);
      gll16(Bhi + offB[r] + k0, &lds[LDS_BH + ldso[r]]);
      gll16(Blo + offB[r] + k0, &lds[LDS_BL + ldso[r]]);
    }
    __syncthreads();

    #pragma unroll
    for (int kh = 0; kh < 2; ++kh) {
      bf16x8 ah[4], al[4], bh[4], bl[4];
      #pragma unroll
      for (int i = 0; i < 4; ++i) {
        int off = (wm * 64 + i * 16 + lr) * 64 + kh * 32 + lg * 8;
        ah[i] = *(const bf16x8*)&lds[LDS_AH + off];
        al[i] = *(const bf16x8*)&lds[LDS_AL + off];
      }
      #pragma unroll
      for (int j = 0; j < 4; ++j) {
        int off = (wn * 64 + j * 16 + lr) * 64 + kh * 32 + lg * 8;
        bh[j] = *(const bf16x8*)&lds[LDS_BH + off];
        bl[j] = *(const bf16x8*)&lds[LDS_BL + off];
      }
      #pragma unroll
      for (int i = 0; i < 4; ++i)
        #pragma unroll
        for (int j = 0; j < 4; ++j) {
          acc[i][j] = __builtin_amdgcn_mfma_f32_16x16x32_bf16(ah[i], bh[j], acc[i][j], 0, 0, 0);
          acc[i][j] = __builtin_amdgcn_mfma_f32_16x16x32_bf16(ah[i], bl[j], acc[i][j], 0, 0, 0);
          acc[i][j] = __builtin_amdgcn_mfma_f32_16x16x32_bf16(al[i], bh[j], acc[i][j], 0, 0, 0);
        }
    }
    __syncthreads();
  }

  // epilogue: scale by inverse norms, scattered dword stores (C/D: col=lane&15,
  // row=(lane>>4)*4+reg  [m89-verified])
  const float* invP = ws_ro + WS_INVP;
  const float* invK = ws_ro + WS_INVK;
  #pragma unroll
  for (int i = 0; i < 4; ++i) {
    #pragma unroll
    for (int q = 0; q < 4; ++q) {
      int row = bm0 + wm * 64 + i * 16 + lg * 4 + q;
      float ip = invP[row];
      #pragma unroll
      for (int j = 0; j < 4; ++j) {
        int col = bn0 + wn * 64 + j * 16 + lr;
        C[(size_t)row * PP + col] = acc[i][j][q] * ip * invK[col];
      }
    }
  }
}

// ---------- Fallback fp32 path (used only if ws_size too small) -------------
__global__ __launch_bounds__(256) void norms_kernel(const float* __restrict__ ppg,
                                                    const float* __restrict__ keys,
                                                    float* __restrict__ ws) {
  int blk = blockIdx.x;
  const float* src; float* dst;
  if (blk < PP) { src = keys + (size_t)blk * DD; dst = ws + WS_INVK + blk; }
  else          { src = ppg + (size_t)(blk - PP) * DD; dst = ws + WS_INVP + (blk - PP); }
  int t = threadIdx.x;
  float4 v = ((const float4*)src)[t];
  float s = v.x*v.x + v.y*v.y + v.z*v.z + v.w*v.w;
  __shared__ float red[4];
  #pragma unroll
  for (int o = 32; o > 0; o >>= 1) s += __shfl_down(s, o);
  if ((t & 63) == 0) red[t >> 6] = s;
  __syncthreads();
  if (t == 0) {
    float tot = red[0] + red[1] + red[2] + red[3];
    *dst = 1.0f / fmaxf(sqrtf(tot), 1e-8f);
  }
}

#define BM 128
#define BN 128
#define BK 16
__global__ __launch_bounds__(256) void gemm_kernel(const float* __restrict__ A,
                                                   const float* __restrict__ B,
                                                   const float* __restrict__ ws,
                                                   float* __restrict__ C) {
  __shared__ float As[BK][BM];
  __shared__ float Bs[BK][BN];
  int t = threadIdx.x;
  int bm0 = (blockIdx.x / (PP / BN)) * BM;
  int bn0 = (blockIdx.x % (PP / BN)) * BN;
  int tx = t & 15, ty = t >> 4;
  float acc[8][8] = {};
  int r = t & 127;
  const float* src = (t < 128) ? (A + (size_t)(bm0 + r) * DD)
                               : (B + (size_t)(bn0 + r) * DD);
  float* dstbase = (t < 128) ? &As[0][0] : &Bs[0][0];
  for (int k0 = 0; k0 < DD; k0 += BK) {
    #pragma unroll
    for (int q = 0; q < 4; ++q) {
      float4 v = *(const float4*)(src + k0 + q * 4);
      dstbase[(q * 4 + 0) * 128 + r] = v.x;
      dstbase[(q * 4 + 1) * 128 + r] = v.y;
      dstbase[(q * 4 + 2) * 128 + r] = v.z;
      dstbase[(q * 4 + 3) * 128 + r] = v.w;
    }
    __syncthreads();
    #pragma unroll
    for (int kk = 0; kk < BK; ++kk) {
      float a[8], b[8];
      *(float4*)&a[0] = *(const float4*)&As[kk][ty * 8];
      *(float4*)&a[4] = *(const float4*)&As[kk][ty * 8 + 4];
      *(float4*)&b[0] = *(const float4*)&Bs[kk][tx * 8];
      *(float4*)&b[4] = *(const float4*)&Bs[kk][tx * 8 + 4];
      #pragma unroll
      for (int i = 0; i < 8; ++i)
        #pragma unroll
        for (int j = 0; j < 8; ++j)
          acc[i][j] = fmaf(a[i], b[j], acc[i][j]);
    }
    __syncthreads();
  }
  const float* invK = ws + WS_INVK;
  const float* invP = ws + WS_INVP;
  #pragma unroll
  for (int i = 0; i < 8; ++i) {
    int row = bm0 + ty * 8 + i;
    float ia = invP[row];
    #pragma unroll
    for (int j = 0; j < 8; j += 4) {
      int col = bn0 + tx * 8 + j;
      float4 o;
      o.x = acc[i][j + 0] * ia * invK[col + 0];
      o.y = acc[i][j + 1] * ia * invK[col + 1];
      o.z = acc[i][j + 2] * ia * invK[col + 2];
      o.w = acc[i][j + 3] * ia * invK[col + 3];
      *(float4*)(C + (size_t)row * PP + col) = o;
    }
  }
}

// ---------- Kernel 3: per-row top-8 + entropy -------------------------------
__global__ __launch_bounds__(256) void topk_kernel(const float* __restrict__ cosm,
                                                   float* __restrict__ ws) {
  int row = blockIdx.x;
  int t = threadIdx.x;
  const float* crow = cosm + (size_t)row * PP;
  float4 cv = ((const float4*)crow)[t];
  float c[4] = {cv.x, cv.y, cv.z, cv.w};

  __shared__ float redf[4];
  __shared__ float redz[4], redw[4];

  float mn = fminf(fminf(c[0], c[1]), fminf(c[2], c[3]));
  float rr = mn;
  #pragma unroll
  for (int o = 32; o > 0; o >>= 1) rr = fminf(rr, __shfl_down(rr, o));
  if ((t & 63) == 0) redf[t >> 6] = rr;
  __syncthreads();
  float m = 1.0f - fminf(fminf(redf[0], redf[1]), fminf(redf[2], redf[3]));

  float z = 0.f, w = 0.f;
  #pragma unroll
  for (int j = 0; j < 4; ++j) {
    float s = 1.0f - c[j];
    float e = expf(s - m);
    z += e;
    w += s * e;
  }
  #pragma unroll
  for (int o = 32; o > 0; o >>= 1) { z += __shfl_down(z, o); w += __shfl_down(w, o); }
  if ((t & 63) == 0) { redz[t >> 6] = z; redw[t >> 6] = w; }
  __syncthreads();
  if (t == 0) {
    float zT = redz[0] + redz[1] + redz[2] + redz[3];
    float wT = redw[0] + redw[1] + redw[2] + redw[3];
    ws[WS_ENT + row] = m + logf(zT) - wT / zT;
  }

  __shared__ float wv[4];
  __shared__ int wi[4];
  __shared__ float bval;
  __shared__ int bidx;
  __shared__ int sel[KSEL];
  unsigned used = 0;
  float score_sum = 0.f;

  for (int it = 0; it < KSEL; ++it) {
    float v = -1e30f; int vi = -1;
    #pragma unroll
    for (int j = 0; j < 4; ++j) {
      if (!((used >> j) & 1)) {
        float cj = c[j];
        int gi = t * 4 + j;
        if (cj > v || (cj == v && gi < vi)) { v = cj; vi = gi; }
      }
    }
    #pragma unroll
    for (int o = 32; o > 0; o >>= 1) {
      float ov = __shfl_down(v, o);
      int oi = __shfl_down(vi, o);
      if (ov > v || (ov == v && oi >= 0 && (vi < 0 || oi < vi))) { v = ov; vi = oi; }
    }
    if ((t & 63) == 0) { wv[t >> 6] = v; wi[t >> 6] = vi; }
    __syncthreads();
    if (t == 0) {
      float bv = wv[0]; int bi = wi[0];
      #pragma unroll
      for (int q = 1; q < 4; ++q)
        if (wv[q] > bv || (wv[q] == bv && wi[q] < bi)) { bv = wv[q]; bi = wi[q]; }
      bval = bv; bidx = bi; sel[it] = bi;
    }
    __syncthreads();
    int bi = bidx;
    score_sum += 1.0f - bval;
    if ((bi >> 2) == t) used |= 1u << (bi & 3);
    __syncthreads();
  }

  if (t == 0) ws[WS_SCORE + row] = score_sum;
  if (t < KSEL) ((int*)(ws + WS_IDX))[row * KSEL + t] = sel[t];
}

// ---------- Kernel 4: gather + conv + mean + normalize + add ----------------
__global__ __launch_bounds__(256) void prompt_kernel(const float* __restrict__ ppg,
                                                     const float* __restrict__ pool,
                                                     const float* __restrict__ cw,
                                                     const float* __restrict__ cb,
                                                     const float* __restrict__ ws,
                                                     float* __restrict__ out) {
  int row = blockIdx.x;
  int t = threadIdx.x;
  const int* idx = (const int*)(ws + WS_IDX) + row * KSEL;
  float w0 = cw[0], w1 = cw[1], w2 = cw[2], bb = cb[0];
  int d0 = t * 4;

  float a0 = 0.f, a1 = 0.f, a2 = 0.f, a3 = 0.f;
  #pragma unroll
  for (int j = 0; j < KSEL; ++j) {
    int r = idx[j];
    const float* src = pool + (size_t)r * DD;
    float4 x = *(const float4*)(src + d0);
    float xm = (d0 > 0) ? src[d0 - 1] : 0.f;
    float xp = (d0 + 4 < DD) ? src[d0 + 4] : 0.f;
    float y0 = fmaf(w0, xm,  fmaf(w1, x.x, fmaf(w2, x.y, bb)));
    float y1 = fmaf(w0, x.x, fmaf(w1, x.y, fmaf(w2, x.z, bb)));
    float y2 = fmaf(w0, x.y, fmaf(w1, x.z, fmaf(w2, x.w, bb)));
    float y3 = fmaf(w0, x.z, fmaf(w1, x.w, fmaf(w2, xp, bb)));
    a0 += fmaxf(y0, 0.f);
    a1 += fmaxf(y1, 0.f);
    a2 += fmaxf(y2, 0.f);
    a3 += fmaxf(y3, 0.f);
  }
  float p0 = a0 * 0.125f, p1 = a1 * 0.125f, p2 = a2 * 0.125f, p3 = a3 * 0.125f;

  __shared__ float rmin[4], rmax[4];
  float lmin = fminf(fminf(p0, p1), fminf(p2, p3));
  float lmax = fmaxf(fmaxf(p0, p1), fmaxf(p2, p3));
  #pragma unroll
  for (int o = 32; o > 0; o >>= 1) {
    lmin = fminf(lmin, __shfl_down(lmin, o));
    lmax = fmaxf(lmax, __shfl_down(lmax, o));
  }
  if ((t & 63) == 0) { rmin[t >> 6] = lmin; rmax[t >> 6] = lmax; }
  __syncthreads();
  float pmin = fminf(fminf(rmin[0], rmin[1]), fminf(rmin[2], rmin[3]));
  float pmax = fmaxf(fmaxf(rmax[0], rmax[1]), fmaxf(rmax[2], rmax[3]));
  float scale = 2.0f / (pmax - pmin);

  float4 pv = *(const float4*)(ppg + (size_t)row * DD + d0);
  float4 o;
  o.x = pv.x + (scale * (p0 - pmin) - 1.0f);
  o.y = pv.y + (scale * (p1 - pmin) - 1.0f);
  o.z = pv.z + (scale * (p2 - pmin) - 1.0f);
  o.w = pv.w + (scale * (p3 - pmin) - 1.0f);
  *(float4*)(out + (size_t)row * DD + d0) = o;
}

// ---------- Kernel 5: deterministic final reduction -------------------------
__global__ __launch_bounds__(256) void finalize_kernel(const float* __restrict__ ws,
                                                       float* __restrict__ out) {
  int t = threadIdx.x;
  const float* ss = ws + WS_SCORE;
  const float* ee = ws + WS_ENT;
  float s = 0.f, e = 0.f;
  for (int i = t; i < BZ; i += 256) { s += ss[i]; e += ee[i]; }
  __shared__ float rs[4], re[4];
  #pragma unroll
  for (int o = 32; o > 0; o >>= 1) { s += __shfl_down(s, o); e += __shfl_down(e, o); }
  if ((t & 63) == 0) { rs[t >> 6] = s; re[t >> 6] = e; }
  __syncthreads();
  if (t == 0) {
    float sT = rs[0] + rs[1] + rs[2] + rs[3];
    float eT = re[0] + re[1] + re[2] + re[3];
    out[(size_t)BZ * DD + 0] = sT / (float)(BZ * KSEL);
    out[(size_t)BZ * DD + 1] = eT / (float)BZ;
  }
}

extern "C" void kernel_launch(void* const* d_in, const int* in_sizes, int n_in,
                              void* d_out, int out_size, void* d_ws, size_t ws_size,
                              hipStream_t stream) {
  const float* ppg  = (const float*)d_in[0];
  const float* keys = (const float*)d_in[1];
  const float* pool = (const float*)d_in[2];
  const float* cw   = (const float*)d_in[3];
  const float* cb   = (const float*)d_in[4];
  float* out = (float*)d_out;
  float* ws  = (float*)d_ws;

  if (ws_size >= WS_NEED) {
    hipLaunchKernelGGL(convert_kernel, dim3(PP + BZ), dim3(256), 0, stream, ppg, keys, ws);
    hipLaunchKernelGGL(gemm_mfma, dim3((BZ / 128) * (PP / 128)), dim3(256), 0, stream, ws, out);
  } else {
    hipLaunchKernelGGL(norms_kernel, dim3(PP + BZ), dim3(256), 0, stream, ppg, keys, ws);
    hipLaunchKernelGGL(gemm_kernel, dim3((BZ / BM) * (PP / BN)), dim3(256), 0, stream,
                       ppg, keys, ws, out);
  }
  hipLaunchKernelGGL(topk_kernel, dim3(BZ), dim3(256), 0, stream, out, ws);
  hipLaunchKernelGGL(prompt_kernel, dim3(BZ), dim3(256), 0, stream, ppg, pool, cw, cb, ws, out);
  hipLaunchKernelGGL(finalize_kernel, dim3(1), dim3(256), 0, stream, ws, out);
}

// Round 3
// 146.154 us; speedup vs baseline: 2.2824x; 1.1940x over previous
//
#include <hip/hip_runtime.h>
#include <hip/hip_bf16.h>

#define BZ 8192
#define PP 1024
#define DD 1024
#define KSEL 8

typedef unsigned short u16;
typedef __attribute__((ext_vector_type(8))) short bf16x8;
typedef __attribute__((ext_vector_type(4))) float f32x4;

// ws layout (floats):
//   [0,1024)       inv-norm keys
//   [1024,9216)    inv-norm ppg
//   [9216,17408)   per-row top-8 score sum
//   [17408,25600)  per-row entropy
//   [25600,91136)  top-8 indices (ints)
//   byte 368640 .. : bf16 A_hi, A_lo (16MB each), B_hi, B_lo (2MB each)
#define WS_INVK 0
#define WS_INVP 1024
#define WS_SCORE 9216
#define WS_ENT 17408
#define WS_IDX 25600
#define WS_BF16_BYTE 368640ull
#define WS_NEED (WS_BF16_BYTE + 2ull*16777216ull + 2ull*4194304ull)

__device__ __forceinline__ u16 f2bf(float x) {
  __hip_bfloat16 h = __float2bfloat16(x);
  return *(u16*)&h;
}
__device__ __forceinline__ float bf2f(u16 u) {
  __hip_bfloat16 h; *(u16*)&h = u;
  return __bfloat162float(h);
}
__device__ __forceinline__ void gll16(const void* g, void* l) {
  __builtin_amdgcn_global_load_lds((__attribute__((address_space(1))) void*)g,
                                   (__attribute__((address_space(3))) void*)l, 16, 0, 0);
}

// ---------- Kernel 1: fused fp32->bf16 hi/lo conversion + inverse norms ------
__global__ __launch_bounds__(256) void convert_kernel(const float* __restrict__ ppg,
                                                      const float* __restrict__ keys,
                                                      float* __restrict__ ws) {
  u16* Ahi = (u16*)((char*)ws + WS_BF16_BYTE);
  u16* Alo = Ahi + 8388608;
  u16* Bhi = Alo + 8388608;
  u16* Blo = Bhi + 1048576;

  int blk = blockIdx.x;
  const float* src; u16 *hi, *lo; float* invdst;
  if (blk < PP) {
    src = keys + (size_t)blk * DD;
    hi = Bhi + (size_t)blk * DD; lo = Blo + (size_t)blk * DD;
    invdst = ws + WS_INVK + blk;
  } else {
    int r = blk - PP;
    src = ppg + (size_t)r * DD;
    hi = Ahi + (size_t)r * DD; lo = Alo + (size_t)r * DD;
    invdst = ws + WS_INVP + r;
  }
  int t = threadIdx.x;
  float4 v = ((const float4*)src)[t];
  float x[4] = {v.x, v.y, v.z, v.w};
  u16 h4[4], l4[4];
  float s = 0.f;
  #pragma unroll
  for (int j = 0; j < 4; ++j) {
    h4[j] = f2bf(x[j]);
    l4[j] = f2bf(x[j] - bf2f(h4[j]));
    s += x[j] * x[j];
  }
  *(ushort4*)(hi + t * 4) = *(ushort4*)h4;
  *(ushort4*)(lo + t * 4) = *(ushort4*)l4;

  __shared__ float red[4];
  #pragma unroll
  for (int o = 32; o > 0; o >>= 1) s += __shfl_down(s, o);
  if ((t & 63) == 0) red[t >> 6] = s;
  __syncthreads();
  if (t == 0) {
    float tot = red[0] + red[1] + red[2] + red[3];
    *invdst = 1.0f / fmaxf(sqrtf(tot), 1e-8f);
  }
}

// ---------- Kernel 2: 3-pass bf16 hi/lo MFMA GEMM (m97 structure) -----------
#define LDS_AH 0
#define LDS_AL 8192
#define LDS_BH 16384
#define LDS_BL 24576

__global__ __launch_bounds__(256, 2) void gemm_mfma(const float* __restrict__ ws_ro,
                                                    float* __restrict__ C) {
  const u16* Ahi = (const u16*)((const char*)ws_ro + WS_BF16_BYTE);
  const u16* Alo = Ahi + 8388608;
  const u16* Bhi = Alo + 8388608;
  const u16* Blo = Bhi + 1048576;

  __shared__ u16 lds[32768];  // 64 KB: Ahi|Alo|Bhi|Blo tiles, each 128x64 bf16

  int t = threadIdx.x;
  int wid = t >> 6, lane = t & 63;
  int lr = lane & 15, lg = lane >> 4;

  int orig = blockIdx.x;
  int wg = (orig & 7) * 64 + (orig >> 3);
  int bm0 = (wg >> 3) * 128;
  int bn0 = (wg & 7) * 128;

  int wm = wid >> 1, wn = wid & 1;

  size_t offA[4], offB[4];
  int ldso[4];
  #pragma unroll
  for (int r = 0; r < 4; ++r) {
    int s = r * 256 + t;
    int row = s >> 3, g = s & 7;
    offA[r] = (size_t)(bm0 + row) * DD + g * 8;
    offB[r] = (size_t)(bn0 + row) * DD + g * 8;
    ldso[r] = (r * 256 + wid * 64) * 8;
  }

  f32x4 acc[4][4] = {};

  for (int kt = 0; kt < 16; ++kt) {
    int k0 = kt * 64;
    #pragma unroll
    for (int r = 0; r < 4; ++r) {
      gll16(Ahi + offA[r] + k0, &lds[LDS_AH + ldso[r]]);
      gll16(Alo + offA[r] + k0, &lds[LDS_AL + ldso[r]]);
      gll16(Bhi + offB[r] + k0, &lds[LDS_BH + ldso[r]]);
      gll16(Blo + offB[r] + k0, &lds[LDS_BL + ldso[r]]);
    }
    __syncthreads();

    #pragma unroll
    for (int kh = 0; kh < 2; ++kh) {
      bf16x8 ah[4], al[4], bh[4], bl[4];
      #pragma unroll
      for (int i = 0; i < 4; ++i) {
        int off = (wm * 64 + i * 16 + lr) * 64 + kh * 32 + lg * 8;
        ah[i] = *(const bf16x8*)&lds[LDS_AH + off];
        al[i] = *(const bf16x8*)&lds[LDS_AL + off];
      }
      #pragma unroll
      for (int j = 0; j < 4; ++j) {
        int off = (wn * 64 + j * 16 + lr) * 64 + kh * 32 + lg * 8;
        bh[j] = *(const bf16x8*)&lds[LDS_BH + off];
        bl[j] = *(const bf16x8*)&lds[LDS_BL + off];
      }
      #pragma unroll
      for (int i = 0; i < 4; ++i)
        #pragma unroll
        for (int j = 0; j < 4; ++j) {
          acc[i][j] = __builtin_amdgcn_mfma_f32_16x16x32_bf16(ah[i], bh[j], acc[i][j], 0, 0, 0);
          acc[i][j] = __builtin_amdgcn_mfma_f32_16x16x32_bf16(ah[i], bl[j], acc[i][j], 0, 0, 0);
          acc[i][j] = __builtin_amdgcn_mfma_f32_16x16x32_bf16(al[i], bh[j], acc[i][j], 0, 0, 0);
        }
    }
    __syncthreads();
  }

  const float* invP = ws_ro + WS_INVP;
  const float* invK = ws_ro + WS_INVK;
  #pragma unroll
  for (int i = 0; i < 4; ++i) {
    #pragma unroll
    for (int q = 0; q < 4; ++q) {
      int row = bm0 + wm * 64 + i * 16 + lg * 4 + q;
      float ip = invP[row];
      #pragma unroll
      for (int j = 0; j < 4; ++j) {
        int col = bn0 + wn * 64 + j * 16 + lr;
        C[(size_t)row * PP + col] = acc[i][j][q] * ip * invK[col];
      }
    }
  }
}

// ---------- Fallback fp32 GEMM path (only if ws too small) ------------------
__global__ __launch_bounds__(256) void norms_kernel(const float* __restrict__ ppg,
                                                    const float* __restrict__ keys,
                                                    float* __restrict__ ws) {
  int blk = blockIdx.x;
  const float* src; float* dst;
  if (blk < PP) { src = keys + (size_t)blk * DD; dst = ws + WS_INVK + blk; }
  else          { src = ppg + (size_t)(blk - PP) * DD; dst = ws + WS_INVP + (blk - PP); }
  int t = threadIdx.x;
  float4 v = ((const float4*)src)[t];
  float s = v.x*v.x + v.y*v.y + v.z*v.z + v.w*v.w;
  __shared__ float red[4];
  #pragma unroll
  for (int o = 32; o > 0; o >>= 1) s += __shfl_down(s, o);
  if ((t & 63) == 0) red[t >> 6] = s;
  __syncthreads();
  if (t == 0) {
    float tot = red[0] + red[1] + red[2] + red[3];
    *dst = 1.0f / fmaxf(sqrtf(tot), 1e-8f);
  }
}

#define BM 128
#define BN 128
#define BK 16
__global__ __launch_bounds__(256) void gemm_kernel(const float* __restrict__ A,
                                                   const float* __restrict__ B,
                                                   const float* __restrict__ ws,
                                                   float* __restrict__ C) {
  __shared__ float As[BK][BM];
  __shared__ float Bs[BK][BN];
  int t = threadIdx.x;
  int bm0 = (blockIdx.x / (PP / BN)) * BM;
  int bn0 = (blockIdx.x % (PP / BN)) * BN;
  int tx = t & 15, ty = t >> 4;
  float acc[8][8] = {};
  int r = t & 127;
  const float* src = (t < 128) ? (A + (size_t)(bm0 + r) * DD)
                               : (B + (size_t)(bn0 + r) * DD);
  float* dstbase = (t < 128) ? &As[0][0] : &Bs[0][0];
  for (int k0 = 0; k0 < DD; k0 += BK) {
    #pragma unroll
    for (int q = 0; q < 4; ++q) {
      float4 v = *(const float4*)(src + k0 + q * 4);
      dstbase[(q * 4 + 0) * 128 + r] = v.x;
      dstbase[(q * 4 + 1) * 128 + r] = v.y;
      dstbase[(q * 4 + 2) * 128 + r] = v.z;
      dstbase[(q * 4 + 3) * 128 + r] = v.w;
    }
    __syncthreads();
    #pragma unroll
    for (int kk = 0; kk < BK; ++kk) {
      float a[8], b[8];
      *(float4*)&a[0] = *(const float4*)&As[kk][ty * 8];
      *(float4*)&a[4] = *(const float4*)&As[kk][ty * 8 + 4];
      *(float4*)&b[0] = *(const float4*)&Bs[kk][tx * 8];
      *(float4*)&b[4] = *(const float4*)&Bs[kk][tx * 8 + 4];
      #pragma unroll
      for (int i = 0; i < 8; ++i)
        #pragma unroll
        for (int j = 0; j < 8; ++j)
          acc[i][j] = fmaf(a[i], b[j], acc[i][j]);
    }
    __syncthreads();
  }
  const float* invK = ws + WS_INVK;
  const float* invP = ws + WS_INVP;
  #pragma unroll
  for (int i = 0; i < 8; ++i) {
    int row = bm0 + ty * 8 + i;
    float ia = invP[row];
    #pragma unroll
    for (int j = 0; j < 8; j += 4) {
      int col = bn0 + tx * 8 + j;
      float4 o;
      o.x = acc[i][j + 0] * ia * invK[col + 0];
      o.y = acc[i][j + 1] * ia * invK[col + 1];
      o.z = acc[i][j + 2] * ia * invK[col + 2];
      o.w = acc[i][j + 3] * ia * invK[col + 3];
      *(float4*)(C + (size_t)row * PP + col) = o;
    }
  }
}

// ---------- Kernel 3: wave-per-row top-8 + entropy (no block barriers) ------
__global__ __launch_bounds__(256) void topk_wave_kernel(const float* __restrict__ cosm,
                                                        float* __restrict__ ws) {
  int wid = threadIdx.x >> 6, lane = threadIdx.x & 63;
  int row = blockIdx.x * 4 + wid;
  const float* crow = cosm + (size_t)row * PP;

  // lane holds 16 values: c[p*4+j] = cos[row][p*256 + lane*4 + j]
  float c[16];
  #pragma unroll
  for (int p = 0; p < 4; ++p) {
    float4 v = *(const float4*)(crow + p * 256 + lane * 4);
    c[p * 4 + 0] = v.x; c[p * 4 + 1] = v.y; c[p * 4 + 2] = v.z; c[p * 4 + 3] = v.w;
  }

  // ---- entropy: softmax over score_ = 1 - cos ----
  float mn = c[0];
  #pragma unroll
  for (int l = 1; l < 16; ++l) mn = fminf(mn, c[l]);
  #pragma unroll
  for (int o = 1; o < 64; o <<= 1) mn = fminf(mn, __shfl_xor(mn, o));
  float m = 1.0f - mn;  // max score_

  float z = 0.f, w = 0.f;
  #pragma unroll
  for (int l = 0; l < 16; ++l) {
    float s = 1.0f - c[l];
    float e = expf(s - m);
    z += e;
    w += s * e;
  }
  #pragma unroll
  for (int o = 1; o < 64; o <<= 1) { z += __shfl_xor(z, o); w += __shfl_xor(w, o); }
  if (lane == 0) ws[WS_ENT + row] = m + logf(z) - w / z;

  // ---- top-8 by iterative wave argmax (butterfly -> uniform result) ----
  unsigned used = 0;
  float score_sum = 0.f;
  int myidx = 0;
  #pragma unroll
  for (int it = 0; it < KSEL; ++it) {
    float v = -2.0f; int gi = 1 << 30;
    #pragma unroll
    for (int l = 0; l < 16; ++l) {
      if (!((used >> l) & 1u)) {
        float cv = c[l];
        int g = ((l >> 2) << 8) | (lane << 2) | (l & 3);
        if (cv > v || (cv == v && g < gi)) { v = cv; gi = g; }
      }
    }
    #pragma unroll
    for (int o = 1; o < 64; o <<= 1) {
      float ov = __shfl_xor(v, o);
      int og = __shfl_xor(gi, o);
      if (ov > v || (ov == v && og < gi)) { v = ov; gi = og; }
    }
    score_sum += 1.0f - v;
    if (((gi >> 2) & 63) == lane) used |= 1u << ((((gi >> 8) & 3) << 2) | (gi & 3));
    if (lane == it) myidx = gi;
  }
  if (lane == 0) ws[WS_SCORE + row] = score_sum;
  if (lane < KSEL) ((int*)(ws + WS_IDX))[row * KSEL + lane] = myidx;
}

// ---------- Kernel 4: gather + conv + mean + normalize + add ----------------
__global__ __launch_bounds__(256) void prompt_kernel(const float* __restrict__ ppg,
                                                     const float* __restrict__ pool,
                                                     const float* __restrict__ cw,
                                                     const float* __restrict__ cb,
                                                     const float* __restrict__ ws,
                                                     float* __restrict__ out) {
  int row = blockIdx.x;
  int t = threadIdx.x;
  const int* idx = (const int*)(ws + WS_IDX) + row * KSEL;
  float w0 = cw[0], w1 = cw[1], w2 = cw[2], bb = cb[0];
  int d0 = t * 4;

  float a0 = 0.f, a1 = 0.f, a2 = 0.f, a3 = 0.f;
  #pragma unroll
  for (int j = 0; j < KSEL; ++j) {
    int r = idx[j];
    const float* src = pool + (size_t)r * DD;
    float4 x = *(const float4*)(src + d0);
    float xm = (d0 > 0) ? src[d0 - 1] : 0.f;
    float xp = (d0 + 4 < DD) ? src[d0 + 4] : 0.f;
    float y0 = fmaf(w0, xm,  fmaf(w1, x.x, fmaf(w2, x.y, bb)));
    float y1 = fmaf(w0, x.x, fmaf(w1, x.y, fmaf(w2, x.z, bb)));
    float y2 = fmaf(w0, x.y, fmaf(w1, x.z, fmaf(w2, x.w, bb)));
    float y3 = fmaf(w0, x.z, fmaf(w1, x.w, fmaf(w2, xp, bb)));
    a0 += fmaxf(y0, 0.f);
    a1 += fmaxf(y1, 0.f);
    a2 += fmaxf(y2, 0.f);
    a3 += fmaxf(y3, 0.f);
  }
  float p0 = a0 * 0.125f, p1 = a1 * 0.125f, p2 = a2 * 0.125f, p3 = a3 * 0.125f;

  __shared__ float rmin[4], rmax[4];
  float lmin = fminf(fminf(p0, p1), fminf(p2, p3));
  float lmax = fmaxf(fmaxf(p0, p1), fmaxf(p2, p3));
  #pragma unroll
  for (int o = 32; o > 0; o >>= 1) {
    lmin = fminf(lmin, __shfl_down(lmin, o));
    lmax = fmaxf(lmax, __shfl_down(lmax, o));
  }
  if ((t & 63) == 0) { rmin[t >> 6] = lmin; rmax[t >> 6] = lmax; }
  __syncthreads();
  float pmin = fminf(fminf(rmin[0], rmin[1]), fminf(rmin[2], rmin[3]));
  float pmax = fmaxf(fmaxf(rmax[0], rmax[1]), fmaxf(rmax[2], rmax[3]));
  float scale = 2.0f / (pmax - pmin);

  float4 pv = *(const float4*)(ppg + (size_t)row * DD + d0);
  float4 o;
  o.x = pv.x + (scale * (p0 - pmin) - 1.0f);
  o.y = pv.y + (scale * (p1 - pmin) - 1.0f);
  o.z = pv.z + (scale * (p2 - pmin) - 1.0f);
  o.w = pv.w + (scale * (p3 - pmin) - 1.0f);
  *(float4*)(out + (size_t)row * DD + d0) = o;
}

// ---------- Kernel 5: deterministic final reduction -------------------------
__global__ __launch_bounds__(256) void finalize_kernel(const float* __restrict__ ws,
                                                       float* __restrict__ out) {
  int t = threadIdx.x;
  const float* ss = ws + WS_SCORE;
  const float* ee = ws + WS_ENT;
  float s = 0.f, e = 0.f;
  for (int i = t; i < BZ; i += 256) { s += ss[i]; e += ee[i]; }
  __shared__ float rs[4], re[4];
  #pragma unroll
  for (int o = 32; o > 0; o >>= 1) { s += __shfl_down(s, o); e += __shfl_down(e, o); }
  if ((t & 63) == 0) { rs[t >> 6] = s; re[t >> 6] = e; }
  __syncthreads();
  if (t == 0) {
    float sT = rs[0] + rs[1] + rs[2] + rs[3];
    float eT = re[0] + re[1] + re[2] + re[3];
    out[(size_t)BZ * DD + 0] = sT / (float)(BZ * KSEL);
    out[(size_t)BZ * DD + 1] = eT / (float)BZ;
  }
}

extern "C" void kernel_launch(void* const* d_in, const int* in_sizes, int n_in,
                              void* d_out, int out_size, void* d_ws, size_t ws_size,
                              hipStream_t stream) {
  const float* ppg  = (const float*)d_in[0];
  const float* keys = (const float*)d_in[1];
  const float* pool = (const float*)d_in[2];
  const float* cw   = (const float*)d_in[3];
  const float* cb   = (const float*)d_in[4];
  float* out = (float*)d_out;
  float* ws  = (float*)d_ws;

  if (ws_size >= WS_NEED) {
    hipLaunchKernelGGL(convert_kernel, dim3(PP + BZ), dim3(256), 0, stream, ppg, keys, ws);
    hipLaunchKernelGGL(gemm_mfma, dim3((BZ / 128) * (PP / 128)), dim3(256), 0, stream, ws, out);
  } else {
    hipLaunchKernelGGL(norms_kernel, dim3(PP + BZ), dim3(256), 0, stream, ppg, keys, ws);
    hipLaunchKernelGGL(gemm_kernel, dim3((BZ / BM) * (PP / BN)), dim3(256), 0, stream,
                       ppg, keys, ws, out);
  }
  hipLaunchKernelGGL(topk_wave_kernel, dim3(BZ / 4), dim3(256), 0, stream, out, ws);
  hipLaunchKernelGGL(prompt_kernel, dim3(BZ), dim3(256), 0, stream, ppg, pool, cw, cb, ws, out);
  hipLaunchKernelGGL(finalize_kernel, dim3(1), dim3(256), 0, stream, ws, out);
}